// Round 3
// baseline (3195.116 us; speedup 1.0000x reference)
//
#include <hip/hip_runtime.h>
#include <hip/hip_bf16.h>

#define HD 128
#define RNUM 8

// ---------------- zero / small kernels ----------------
__global__ void zero_f4(float* __restrict__ p, long long n4) {
    long long g = (long long)blockIdx.x * blockDim.x + threadIdx.x;
    if (g < n4) ((float4*)p)[g] = make_float4(0.f, 0.f, 0.f, 0.f);
}

__global__ void count_kernel(const int* __restrict__ ei, const int* __restrict__ et,
                             float* __restrict__ cnt, int E) {
    int e = blockIdx.x * blockDim.x + threadIdx.x;
    if (e < E) atomicAdd(&cnt[ei[E + e] * RNUM + et[e]], 1.0f);
}

__global__ void recip_kernel(float* __restrict__ c, int n) {
    int i = blockIdx.x * blockDim.x + threadIdx.x;
    if (i < n) {
        float v = c[i];
        c[i] = (v > 0.0f) ? (1.0f / v) : 0.0f;
    }
}

__global__ void relu_kernel(float* __restrict__ y, long long n) {
    long long g = (long long)blockIdx.x * blockDim.x + threadIdx.x;
    if (g < n) y[g] = fmaxf(y[g], 0.0f);
}

__global__ void sigmoid_kernel(const float* __restrict__ in, float* __restrict__ out, long long n) {
    long long g = (long long)blockIdx.x * blockDim.x + threadIdx.x;
    if (g < n) out[g] = 1.0f / (1.0f + expf(-in[g]));
}

// ---------------- per-relation edge scatter: t[dst,:] += x[src,:] ----------------
// one thread per (edge, 4-feature chunk); 32 threads (half-wave) per edge so
// the relation check is uniform within each half-wave's edge.
template <bool HAS_IDX>
__global__ void scatter_rel(const int* __restrict__ ei, const int* __restrict__ et,
                            const int* __restrict__ ids, const float* __restrict__ x,
                            float* __restrict__ t, int E, int r) {
    int g = blockIdx.x * blockDim.x + threadIdx.x;
    int e = g >> 5;
    if (e >= E) return;
    if (et[e] != r) return;
    int f4 = (g & 31) * 4;
    int s = ei[e];
    int d = ei[E + e];
    const float* xs = HAS_IDX ? (x + (size_t)ids[s] * HD) : (x + (size_t)s * HD);
    float4 v = *(const float4*)(xs + f4);
    float* tp = t + (size_t)d * HD + f4;
    atomicAdd(tp + 0, v.x);
    atomicAdd(tp + 1, v.y);
    atomicAdd(tp + 2, v.z);
    atomicAdd(tp + 3, v.w);
}

// ---------------- tiled fp32 GEMM: C[m,:] (+)= rowscale(m) * A[row(m),:] @ B ----------------
// A: [?,128] row-major; B: [128,128] row-major; C: [M,128].
// INIT mode (!ACCUM): C = A@B + bias. ACCUM mode: C += A@B.
// HAS_IDX: row(m) = idx[m] (embedding gather fused). HAS_SCALE: scale = scaleB[m*8].
// ZERO_A: after the K-loop, zero A rows of this block (self-cleaning t buffer).
template <bool ACCUM, bool HAS_IDX, bool HAS_SCALE, bool ZERO_A>
__launch_bounds__(256)
__global__ void gemm128(float* __restrict__ A, const int* __restrict__ idx,
                        const float* __restrict__ scaleB, const float* __restrict__ B,
                        float* __restrict__ C, const float* __restrict__ bias, int M) {
    __shared__ float As[8][132];   // As[k][m]
    __shared__ float Bs[8][132];   // Bs[k][f]

    const int tid = threadIdx.x;
    const int tx = tid & 15;
    const int ty = tid >> 4;
    const int m0 = blockIdx.x * 128;

    const int arow = tid >> 1;         // 0..127
    const int akk  = (tid & 1) * 4;    // 0 or 4
    const int am   = m0 + arow;
    const bool avalid = (am < M);
    const int asrc = avalid ? (HAS_IDX ? idx[am] : am) : 0;
    const float asc = (HAS_SCALE && avalid) ? scaleB[(size_t)am * RNUM] : 1.0f;

    const int brow = tid >> 5;         // 0..7
    const int bcol = (tid & 31) * 4;   // 0..124

    float acc[8][8];
#pragma unroll
    for (int i = 0; i < 8; i++)
#pragma unroll
        for (int j = 0; j < 8; j++) acc[i][j] = 0.0f;

    for (int k0 = 0; k0 < HD; k0 += 8) {
        float4 av = make_float4(0.f, 0.f, 0.f, 0.f);
        if (avalid) av = *(const float4*)(A + (size_t)asrc * HD + k0 + akk);
        As[akk + 0][arow] = av.x * asc;
        As[akk + 1][arow] = av.y * asc;
        As[akk + 2][arow] = av.z * asc;
        As[akk + 3][arow] = av.w * asc;

        *(float4*)&Bs[brow][bcol] = *(const float4*)(B + (size_t)(k0 + brow) * HD + bcol);

        __syncthreads();
#pragma unroll
        for (int k = 0; k < 8; k++) {
            float4 a0 = *(const float4*)&As[k][ty * 8];
            float4 a1 = *(const float4*)&As[k][ty * 8 + 4];
            float4 b0 = *(const float4*)&Bs[k][tx * 8];
            float4 b1 = *(const float4*)&Bs[k][tx * 8 + 4];
            float a[8] = {a0.x, a0.y, a0.z, a0.w, a1.x, a1.y, a1.z, a1.w};
            float b[8] = {b0.x, b0.y, b0.z, b0.w, b1.x, b1.y, b1.z, b1.w};
#pragma unroll
            for (int i = 0; i < 8; i++)
#pragma unroll
                for (int j = 0; j < 8; j++) acc[i][j] = fmaf(a[i], b[j], acc[i][j]);
        }
        __syncthreads();
    }

    if (ZERO_A && avalid) {
        // this block is the only reader of A rows m0..m0+127; zero own row half
        float4* zp = (float4*)(A + (size_t)asrc * HD + (tid & 1) * 64);
#pragma unroll
        for (int q = 0; q < 16; q++) zp[q] = make_float4(0.f, 0.f, 0.f, 0.f);
    }

#pragma unroll
    for (int i = 0; i < 8; i++) {
        int m = m0 + ty * 8 + i;
        if (m >= M) continue;
        size_t base = (size_t)m * HD + tx * 8;
#pragma unroll
        for (int j = 0; j < 8; j++) {
            float v = acc[i][j];
            if (ACCUM) C[base + j] += v;
            else       C[base + j] = v + bias[tx * 8 + j];
        }
    }
}

extern "C" void kernel_launch(void* const* d_in, const int* in_sizes, int n_in,
                              void* d_out, int out_size, void* d_ws, size_t ws_size,
                              hipStream_t stream) {
    const int*   x_ids = (const int*)d_in[0];
    const int*   ei    = (const int*)d_in[1];
    const int*   et    = (const int*)d_in[2];
    float*       emb   = (float*)d_in[3];
    const float* W1    = (const float*)d_in[4];
    const float* root1 = (const float*)d_in[5];
    const float* b1    = (const float*)d_in[6];
    const float* W2    = (const float*)d_in[7];
    const float* root2 = (const float*)d_in[8];
    const float* b2    = (const float*)d_in[9];

    const int N = in_sizes[0];
    const int E = in_sizes[1] / 2;
    float* out = (float*)d_out;

    // workspace: invc [N*8] + t [N*128] + aggB [N*128]  = 105.6 MB
    char* ws = (char*)d_ws;
    float* invc = (float*)ws;                                      // 3.2 MB
    float* t    = (float*)(ws + (size_t)N * RNUM * 4);             // 51.2 MB
    float* aggB = (float*)(ws + (size_t)N * RNUM * 4 + (size_t)N * HD * 4);

    const int gemmGrid = (N + 127) / 128;
    const long long nOut = (long long)N * HD;
    const int scatterGrid = (int)(((long long)E * 32 + 255) / 256);

    // ---- counts -> reciprocals ----
    long long invc4 = (long long)N * RNUM / 4;
    zero_f4<<<(int)((invc4 + 255) / 256), 256, 0, stream>>>(invc, invc4);
    count_kernel<<<(E + 255) / 256, 256, 0, stream>>>(ei, et, invc, E);
    recip_kernel<<<(N * RNUM + 255) / 256, 256, 0, stream>>>(invc, N * RNUM);

    // ---- zero t once; relation GEMMs self-clean it afterwards ----
    long long t4 = nOut / 4;
    zero_f4<<<(int)((t4 + 255) / 256), 256, 0, stream>>>(t, t4);

    // ================= layer 1 (x = emb[x_ids], agg -> d_out) =================
    // root: out = emb[ids] @ root1 + b1   (fused gather)
    gemm128<false, true, false, false><<<gemmGrid, 256, 0, stream>>>(
        emb, x_ids, nullptr, root1, out, b1, N);
    for (int r = 0; r < RNUM; r++) {
        scatter_rel<true><<<scatterGrid, 256, 0, stream>>>(ei, et, x_ids, emb, t, E, r);
        gemm128<true, false, true, true><<<gemmGrid, 256, 0, stream>>>(
            t, nullptr, invc + r, W1 + (size_t)r * HD * HD, out, nullptr, N);
    }
    relu_kernel<<<(int)((nOut + 255) / 256), 256, 0, stream>>>(out, nOut);

    // ================= layer 2 (z = d_out, agg -> aggB) =================
    gemm128<false, false, false, false><<<gemmGrid, 256, 0, stream>>>(
        out, nullptr, nullptr, root2, aggB, b2, N);
    for (int r = 0; r < RNUM; r++) {
        scatter_rel<false><<<scatterGrid, 256, 0, stream>>>(ei, et, nullptr, out, t, E, r);
        gemm128<true, false, true, true><<<gemmGrid, 256, 0, stream>>>(
            t, nullptr, invc + r, W2 + (size_t)r * HD * HD, aggB, nullptr, N);
    }
    sigmoid_kernel<<<(int)((nOut + 255) / 256), 256, 0, stream>>>(aggB, out, nOut);
}

// Round 4
// 1525.555 us; speedup vs baseline: 2.0944x; 2.0944x over previous
//
#include <hip/hip_runtime.h>
#include <hip/hip_bf16.h>

#define HD 128
#define RNUM 8
#define SCAN_BS 2048   // elements per scan block

// ---------------- zero / small kernels ----------------
__global__ void zero_i(int* __restrict__ p, int n) {
    int g = blockIdx.x * blockDim.x + threadIdx.x;
    if (g < n) p[g] = 0;
}

__global__ void relu_kernel(float* __restrict__ y, long long n) {
    long long g = (long long)blockIdx.x * blockDim.x + threadIdx.x;
    if (g < n) y[g] = fmaxf(y[g], 0.0f);
}

__global__ void sigmoid_kernel(const float* __restrict__ in, float* __restrict__ out, long long n) {
    long long g = (long long)blockIdx.x * blockDim.x + threadIdx.x;
    if (g < n) out[g] = 1.0f / (1.0f + expf(-in[g]));
}

// ---------------- CSR build: count -> scan -> fill ----------------
__global__ void count_kernel(const int* __restrict__ ei, const int* __restrict__ et,
                             int* __restrict__ cnt, int E, int N) {
    int e = blockIdx.x * blockDim.x + threadIdx.x;
    if (e < E) atomicAdd(&cnt[et[e] * N + ei[E + e]], 1);
}

// exclusive scan, stage 1: per-block scan of SCAN_BS elems + block totals
__global__ void scan1(const int* __restrict__ in, int* __restrict__ out,
                      int* __restrict__ bsum, int n) {
    __shared__ int s[256];
    const int tid = threadIdx.x;
    const int base = blockIdx.x * SCAN_BS + tid * 8;
    int v[8];
    int sum = 0;
#pragma unroll
    for (int j = 0; j < 8; j++) {
        int x = (base + j < n) ? in[base + j] : 0;
        v[j] = sum;          // exclusive within thread
        sum += x;
    }
    s[tid] = sum;
    __syncthreads();
    for (int off = 1; off < 256; off <<= 1) {
        int tv = (tid >= off) ? s[tid - off] : 0;
        __syncthreads();
        if (tid >= off) s[tid] += tv;
        __syncthreads();
    }
    int excl = (tid > 0) ? s[tid - 1] : 0;
    if (tid == 255) bsum[blockIdx.x] = s[255];
#pragma unroll
    for (int j = 0; j < 8; j++)
        if (base + j < n) out[base + j] = v[j] + excl;
}

// stage 2: exclusive scan of block sums (single block, nb <= 512)
__global__ void scan2(int* __restrict__ bsum, int nb) {
    __shared__ int s[512];
    const int tid = threadIdx.x;
    s[tid] = (tid < nb) ? bsum[tid] : 0;
    __syncthreads();
    for (int off = 1; off < 512; off <<= 1) {
        int tv = (tid >= off) ? s[tid - off] : 0;
        __syncthreads();
        if (tid >= off) s[tid] += tv;
        __syncthreads();
    }
    if (tid < nb) bsum[tid] = (tid > 0) ? s[tid - 1] : 0;
}

// stage 3: add block offsets; also mirror into cursor array for fill
__global__ void scan3(int* __restrict__ out, int* __restrict__ cur,
                      const int* __restrict__ bsum, int n) {
    const int base = blockIdx.x * SCAN_BS + threadIdx.x * 8;
    const int add = bsum[blockIdx.x];
#pragma unroll
    for (int j = 0; j < 8; j++) {
        int i = base + j;
        if (i < n) {
            int v = out[i] + add;
            out[i] = v;
            cur[i] = v;
        }
    }
}

__global__ void fill_kernel(const int* __restrict__ ei, const int* __restrict__ et,
                            int* __restrict__ cur, int* __restrict__ col, int E, int N) {
    int e = blockIdx.x * blockDim.x + threadIdx.x;
    if (e < E) {
        int pos = atomicAdd(&cur[et[e] * N + ei[E + e]], 1);
        col[pos] = ei[e];   // src
    }
}

// ---------------- aggregation: t[d,:] = mean over segment (r,d) of x[src,:] ----------------
// one wave (64 lanes) per dst node, float2 per lane; no atomics, coalesced writes.
template <bool HAS_IDX>
__global__ void agg_rel(const int* __restrict__ row_start, const int* __restrict__ col,
                        const int* __restrict__ ids, const float* __restrict__ x,
                        float* __restrict__ t, int N, int E, int r) {
    int w = (blockIdx.x * blockDim.x + threadIdx.x) >> 6;
    if (w >= N) return;
    int lane = threadIdx.x & 63;
    int seg = r * N + w;
    int s0 = row_start[seg];
    int s1 = (seg == RNUM * N - 1) ? E : row_start[seg + 1];

    float2 a0 = make_float2(0.f, 0.f), a1 = make_float2(0.f, 0.f);
    int e = s0;
    for (; e + 1 < s1; e += 2) {
        int c0 = col[e], c1 = col[e + 1];
        if (HAS_IDX) { c0 = ids[c0]; c1 = ids[c1]; }
        float2 v0 = *(const float2*)(x + (size_t)c0 * HD + lane * 2);
        float2 v1 = *(const float2*)(x + (size_t)c1 * HD + lane * 2);
        a0.x += v0.x; a0.y += v0.y;
        a1.x += v1.x; a1.y += v1.y;
    }
    if (e < s1) {
        int c = col[e];
        if (HAS_IDX) c = ids[c];
        float2 v = *(const float2*)(x + (size_t)c * HD + lane * 2);
        a0.x += v.x; a0.y += v.y;
    }
    float inv = (s1 > s0) ? (1.0f / (float)(s1 - s0)) : 0.0f;
    float2 o = make_float2((a0.x + a1.x) * inv, (a0.y + a1.y) * inv);
    *(float2*)(t + (size_t)w * HD + lane * 2) = o;
}

// ---------------- tiled fp32 GEMM: C[m,:] (+)= A[row(m),:] @ B ----------------
template <bool ACCUM, bool HAS_IDX>
__launch_bounds__(256)
__global__ void gemm128(const float* __restrict__ A, const int* __restrict__ idx,
                        const float* __restrict__ B, float* __restrict__ C,
                        const float* __restrict__ bias, int M) {
    __shared__ float As[8][132];   // As[k][m]
    __shared__ float Bs[8][132];   // Bs[k][f]

    const int tid = threadIdx.x;
    const int tx = tid & 15;
    const int ty = tid >> 4;
    const int m0 = blockIdx.x * 128;

    const int arow = tid >> 1;
    const int akk  = (tid & 1) * 4;
    const int am   = m0 + arow;
    const bool avalid = (am < M);
    const int asrc = avalid ? (HAS_IDX ? idx[am] : am) : 0;

    const int brow = tid >> 5;
    const int bcol = (tid & 31) * 4;

    float acc[8][8];
#pragma unroll
    for (int i = 0; i < 8; i++)
#pragma unroll
        for (int j = 0; j < 8; j++) acc[i][j] = 0.0f;

    for (int k0 = 0; k0 < HD; k0 += 8) {
        float4 av = make_float4(0.f, 0.f, 0.f, 0.f);
        if (avalid) av = *(const float4*)(A + (size_t)asrc * HD + k0 + akk);
        As[akk + 0][arow] = av.x;
        As[akk + 1][arow] = av.y;
        As[akk + 2][arow] = av.z;
        As[akk + 3][arow] = av.w;

        *(float4*)&Bs[brow][bcol] = *(const float4*)(B + (size_t)(k0 + brow) * HD + bcol);

        __syncthreads();
#pragma unroll
        for (int k = 0; k < 8; k++) {
            float4 q0 = *(const float4*)&As[k][ty * 8];
            float4 q1 = *(const float4*)&As[k][ty * 8 + 4];
            float4 r0 = *(const float4*)&Bs[k][tx * 8];
            float4 r1 = *(const float4*)&Bs[k][tx * 8 + 4];
            float a[8] = {q0.x, q0.y, q0.z, q0.w, q1.x, q1.y, q1.z, q1.w};
            float b[8] = {r0.x, r0.y, r0.z, r0.w, r1.x, r1.y, r1.z, r1.w};
#pragma unroll
            for (int i = 0; i < 8; i++)
#pragma unroll
                for (int j = 0; j < 8; j++) acc[i][j] = fmaf(a[i], b[j], acc[i][j]);
        }
        __syncthreads();
    }

#pragma unroll
    for (int i = 0; i < 8; i++) {
        int m = m0 + ty * 8 + i;
        if (m >= M) continue;
        size_t base = (size_t)m * HD + tx * 8;
#pragma unroll
        for (int j = 0; j < 8; j++) {
            float v = acc[i][j];
            if (ACCUM) C[base + j] += v;
            else       C[base + j] = v + bias[tx * 8 + j];
        }
    }
}

extern "C" void kernel_launch(void* const* d_in, const int* in_sizes, int n_in,
                              void* d_out, int out_size, void* d_ws, size_t ws_size,
                              hipStream_t stream) {
    const int*   x_ids = (const int*)d_in[0];
    const int*   ei    = (const int*)d_in[1];
    const int*   et    = (const int*)d_in[2];
    const float* emb   = (const float*)d_in[3];
    const float* W1    = (const float*)d_in[4];
    const float* root1 = (const float*)d_in[5];
    const float* b1    = (const float*)d_in[6];
    const float* W2    = (const float*)d_in[7];
    const float* root2 = (const float*)d_in[8];
    const float* b2    = (const float*)d_in[9];

    const int N = in_sizes[0];
    const int E = in_sizes[1] / 2;
    const int NS = RNUM * N;                 // number of (r,dst) segments
    float* out = (float*)d_out;

    // ---- workspace layout (~111 MB) ----
    char* ws = (char*)d_ws;
    size_t off = 0;
    int* row_start = (int*)(ws + off); off += (size_t)NS * 4;        // 3.2 MB
    int* cur       = (int*)(ws + off); off += (size_t)NS * 4;        // 3.2 MB
    int* col       = (int*)(ws + off); off += (size_t)E * 4;         // 2.0 MB
    int* bsum      = (int*)(ws + off); off += 4096;
    float* t       = (float*)(ws + off); off += (size_t)N * HD * 4;  // 51.2 MB
    float* aggB    = (float*)(ws + off);                             // 51.2 MB

    const int gemmGrid = (N + 127) / 128;
    const long long nOut = (long long)N * HD;
    const int scanBlocks = (NS + SCAN_BS - 1) / SCAN_BS;
    const int aggGrid = (int)(((long long)N * 64 + 255) / 256);

    // ---- build CSR by (relation, dst) — shared by both layers ----
    zero_i<<<(NS + 255) / 256, 256, 0, stream>>>(cur, NS);
    count_kernel<<<(E + 255) / 256, 256, 0, stream>>>(ei, et, cur, E, N);
    scan1<<<scanBlocks, 256, 0, stream>>>(cur, row_start, bsum, NS);
    scan2<<<1, 512, 0, stream>>>(bsum, scanBlocks);
    scan3<<<scanBlocks, 256, 0, stream>>>(row_start, cur, bsum, NS);
    fill_kernel<<<(E + 255) / 256, 256, 0, stream>>>(ei, et, cur, col, E, N);

    // ================= layer 1 (x = emb[x_ids], agg -> d_out) =================
    gemm128<false, true><<<gemmGrid, 256, 0, stream>>>(emb, x_ids, root1, out, b1, N);
    for (int r = 0; r < RNUM; r++) {
        agg_rel<true><<<aggGrid, 256, 0, stream>>>(row_start, col, x_ids, emb, t, N, E, r);
        gemm128<true, false><<<gemmGrid, 256, 0, stream>>>(
            t, nullptr, W1 + (size_t)r * HD * HD, out, nullptr, N);
    }
    relu_kernel<<<(int)((nOut + 255) / 256), 256, 0, stream>>>(out, nOut);

    // ================= layer 2 (z = d_out, agg -> aggB) =================
    gemm128<false, false><<<gemmGrid, 256, 0, stream>>>(out, nullptr, root2, aggB, b2, N);
    for (int r = 0; r < RNUM; r++) {
        agg_rel<false><<<aggGrid, 256, 0, stream>>>(row_start, col, nullptr, out, t, N, E, r);
        gemm128<true, false><<<gemmGrid, 256, 0, stream>>>(
            t, nullptr, W2 + (size_t)r * HD * HD, aggB, nullptr, N);
    }
    sigmoid_kernel<<<(int)((nOut + 255) / 256), 256, 0, stream>>>(aggB, out, nOut);
}

// Round 5
// 852.199 us; speedup vs baseline: 3.7493x; 1.7901x over previous
//
#include <hip/hip_runtime.h>
#include <hip/hip_bf16.h>

#define HD 128
#define RNUM 8
#define SCAN_BS 2048

typedef __attribute__((ext_vector_type(8))) short short8;
typedef __attribute__((ext_vector_type(4))) float float4e;

__device__ __forceinline__ unsigned short f2bf(float f) {
    unsigned int u = __float_as_uint(f);
    u += 0x7fffu + ((u >> 16) & 1u);   // RNE
    return (unsigned short)(u >> 16);
}

// ---------------- small kernels ----------------
__global__ void zero_i(int* __restrict__ p, int n) {
    int g = blockIdx.x * blockDim.x + threadIdx.x;
    if (g < n) p[g] = 0;
}

// ---------------- CSR build: count -> scan -> fill ----------------
__global__ void count_kernel(const int* __restrict__ ei, const int* __restrict__ et,
                             int* __restrict__ cnt, int E, int N) {
    int e = blockIdx.x * blockDim.x + threadIdx.x;
    if (e < E) atomicAdd(&cnt[et[e] * N + ei[E + e]], 1);
}

__global__ void scan1(const int* __restrict__ in, int* __restrict__ out,
                      int* __restrict__ bsum, int n) {
    __shared__ int s[256];
    const int tid = threadIdx.x;
    const int base = blockIdx.x * SCAN_BS + tid * 8;
    int v[8];
    int sum = 0;
#pragma unroll
    for (int j = 0; j < 8; j++) {
        int x = (base + j < n) ? in[base + j] : 0;
        v[j] = sum;
        sum += x;
    }
    s[tid] = sum;
    __syncthreads();
    for (int off = 1; off < 256; off <<= 1) {
        int tv = (tid >= off) ? s[tid - off] : 0;
        __syncthreads();
        if (tid >= off) s[tid] += tv;
        __syncthreads();
    }
    int excl = (tid > 0) ? s[tid - 1] : 0;
    if (tid == 255) bsum[blockIdx.x] = s[255];
#pragma unroll
    for (int j = 0; j < 8; j++)
        if (base + j < n) out[base + j] = v[j] + excl;
}

__global__ void scan2(int* __restrict__ bsum, int nb) {
    __shared__ int s[512];
    const int tid = threadIdx.x;
    s[tid] = (tid < nb) ? bsum[tid] : 0;
    __syncthreads();
    for (int off = 1; off < 512; off <<= 1) {
        int tv = (tid >= off) ? s[tid - off] : 0;
        __syncthreads();
        if (tid >= off) s[tid] += tv;
        __syncthreads();
    }
    if (tid < nb) bsum[tid] = (tid > 0) ? s[tid - 1] : 0;
}

__global__ void scan3(int* __restrict__ out, int* __restrict__ cur,
                      const int* __restrict__ bsum, int n) {
    const int base = blockIdx.x * SCAN_BS + threadIdx.x * 8;
    const int add = bsum[blockIdx.x];
#pragma unroll
    for (int j = 0; j < 8; j++) {
        int i = base + j;
        if (i < n) {
            int v = out[i] + add;
            out[i] = v;
            cur[i] = v;
        }
    }
}

__global__ void fill_kernel(const int* __restrict__ ei, const int* __restrict__ et,
                            int* __restrict__ cur, int* __restrict__ col, int E, int N) {
    int e = blockIdx.x * blockDim.x + threadIdx.x;
    if (e < E) {
        int pos = atomicAdd(&cur[et[e] * N + ei[E + e]], 1);
        col[pos] = ei[e];
    }
}

// ---------------- weight pre-transpose to bf16: WT[f][d] = bf16(W[d][f]) ----------------
__global__ void wt_kernel(const float* __restrict__ W, unsigned short* __restrict__ WT,
                          int nmat) {
    int g = blockIdx.x * blockDim.x + threadIdx.x;
    if (g >= nmat * 16384) return;
    int mat = g >> 14;
    int d = (g >> 7) & 127;
    int f = g & 127;
    WT[mat * 16384 + f * 128 + d] = f2bf(W[g]);
}

// ---------------- fused RGCN layer ----------------
// Per block: 128 dst rows x 128 cols of C, accumulated over 9 sources
// (8 relation-mean aggregates + root/self term), bf16 MFMA, fused bias+act.
// LDS swizzle: chunk ck of row m stored at (ck ^ (m&15)) -> conflict-free frag loads.
template <bool HAS_IDX, int ACT>   // ACT: 0 = relu, 1 = sigmoid
__launch_bounds__(256)
__global__ void rgcn_layer(const int* __restrict__ row_start, const int* __restrict__ col,
                           const int* __restrict__ ids, const float* __restrict__ x,
                           const unsigned short* __restrict__ WT,  // [9][128][128] bf16 [s][f][d]
                           const float* __restrict__ bias,
                           float* __restrict__ Cout, int N, int E) {
    __shared__ unsigned short As[128 * 128];  // 32 KB
    __shared__ unsigned short Ws[128 * 128];  // 32 KB

    const int tid = threadIdx.x;
    const int block0 = blockIdx.x * 128;
    const int w = tid >> 6;
    const int lane = tid & 63;
    const int ln15 = lane & 15;
    const int quad = lane >> 4;
    const int rowbase = (w & 1) * 64;
    const int colbase = (w >> 1) * 64;

    float4e acc[4][4];
#pragma unroll
    for (int i = 0; i < 4; i++)
#pragma unroll
        for (int j = 0; j < 4; j++)
#pragma unroll
            for (int q = 0; q < 4; q++) acc[i][j][q] = 0.0f;

    const int srow = tid >> 5;          // 0..7 (8 rows per pass)
    const int f4 = (tid & 31) * 4;      // feature chunk
    const int sck = f4 >> 3;            // LDS chunk of f4

    for (int s = 0; s < 9; s++) {
        // ---------- stage A tile (128 rows x 128 k, bf16, swizzled) ----------
        if (s < RNUM) {
#pragma unroll 1
            for (int p = 0; p < 16; p++) {
                int row = p * 8 + srow;
                int gr = block0 + row;
                float ax = 0.f, ay = 0.f, az = 0.f, aw = 0.f, inv = 0.f;
                if (gr < N) {
                    int seg = s * N + gr;
                    int s0 = row_start[seg];
                    int s1 = (seg == RNUM * N - 1) ? E : row_start[seg + 1];
                    if (s1 > s0) inv = 1.0f / (float)(s1 - s0);
                    for (int e = s0; e < s1; e++) {
                        int c = col[e];
                        if (HAS_IDX) c = ids[c];
                        const float4* xp = (const float4*)(x + (size_t)c * HD + f4);
                        float4 v = *xp;
                        ax += v.x; ay += v.y; az += v.z; aw += v.w;
                    }
                }
                int si = row * 128 + ((sck ^ (row & 15)) << 3) + (f4 & 7);
                ushort4 o;
                o.x = f2bf(ax * inv); o.y = f2bf(ay * inv);
                o.z = f2bf(az * inv); o.w = f2bf(aw * inv);
                *(ushort4*)&As[si] = o;
            }
        } else {
            // root/self term: A = x[row]
#pragma unroll 1
            for (int p = 0; p < 16; p++) {
                int row = p * 8 + srow;
                int gr = block0 + row;
                float4 v = make_float4(0.f, 0.f, 0.f, 0.f);
                if (gr < N) {
                    int c = HAS_IDX ? ids[gr] : gr;
                    v = *(const float4*)(x + (size_t)c * HD + f4);
                }
                int si = row * 128 + ((sck ^ (row & 15)) << 3) + (f4 & 7);
                ushort4 o;
                o.x = f2bf(v.x); o.y = f2bf(v.y); o.z = f2bf(v.z); o.w = f2bf(v.w);
                *(ushort4*)&As[si] = o;
            }
        }

        // ---------- stage W tile (already transposed bf16 in global) ----------
        {
            const unsigned short* Wsrc = WT + s * 16384;
#pragma unroll
            for (int q = 0; q < 8; q++) {
                int chunk = q * 256 + tid;   // 0..2047 chunks of 8 shorts
                int f = chunk >> 4;
                int c = chunk & 15;
                uint4 v = *(const uint4*)(Wsrc + chunk * 8);
                *(uint4*)&Ws[f * 128 + ((c ^ (f & 15)) << 3)] = v;
            }
        }
        __syncthreads();

        // ---------- MFMA: acc += A @ W ----------
#pragma unroll
        for (int k0 = 0; k0 < 4; k0++) {
            short8 af[4], bf[4];
#pragma unroll
            for (int rt = 0; rt < 4; rt++) {
                int m = rowbase + rt * 16 + ln15;
                int ck = k0 * 4 + quad;
                af[rt] = *(const short8*)&As[m * 128 + ((ck ^ (m & 15)) << 3)];
            }
#pragma unroll
            for (int ct = 0; ct < 4; ct++) {
                int n = colbase + ct * 16 + ln15;
                int ck = k0 * 4 + quad;
                bf[ct] = *(const short8*)&Ws[n * 128 + ((ck ^ (n & 15)) << 3)];
            }
#pragma unroll
            for (int rt = 0; rt < 4; rt++)
#pragma unroll
                for (int ct = 0; ct < 4; ct++)
                    acc[rt][ct] = __builtin_amdgcn_mfma_f32_16x16x32_bf16(
                        af[rt], bf[ct], acc[rt][ct], 0, 0, 0);
        }
        __syncthreads();
    }

    // ---------- epilogue: bias + activation, single C write ----------
#pragma unroll
    for (int ct = 0; ct < 4; ct++) {
        int ncol = colbase + ct * 16 + ln15;
        float bv = bias[ncol];
#pragma unroll
        for (int rt = 0; rt < 4; rt++) {
#pragma unroll
            for (int rg = 0; rg < 4; rg++) {
                int rowg = block0 + rowbase + rt * 16 + quad * 4 + rg;
                if (rowg < N) {
                    float v = acc[rt][ct][rg] + bv;
                    v = (ACT == 0) ? fmaxf(v, 0.0f) : (1.0f / (1.0f + expf(-v)));
                    Cout[(size_t)rowg * HD + ncol] = v;
                }
            }
        }
    }
}

extern "C" void kernel_launch(void* const* d_in, const int* in_sizes, int n_in,
                              void* d_out, int out_size, void* d_ws, size_t ws_size,
                              hipStream_t stream) {
    const int*   x_ids = (const int*)d_in[0];
    const int*   ei    = (const int*)d_in[1];
    const int*   et    = (const int*)d_in[2];
    const float* emb   = (const float*)d_in[3];
    const float* W1    = (const float*)d_in[4];
    const float* root1 = (const float*)d_in[5];
    const float* b1    = (const float*)d_in[6];
    const float* W2    = (const float*)d_in[7];
    const float* root2 = (const float*)d_in[8];
    const float* b2    = (const float*)d_in[9];

    const int N = in_sizes[0];
    const int E = in_sizes[1] / 2;
    const int NS = RNUM * N;
    float* out = (float*)d_out;

    // ---- workspace (~60 MB) ----
    char* ws = (char*)d_ws;
    size_t off = 0;
    int* row_start = (int*)(ws + off); off += (size_t)NS * 4;
    int* cur       = (int*)(ws + off); off += (size_t)NS * 4;
    int* col       = (int*)(ws + off); off += (size_t)E * 4;
    int* bsum      = (int*)(ws + off); off += 4096;
    unsigned short* WT = (unsigned short*)(ws + off); off += (size_t)18 * 16384 * 2;
    float* z       = (float*)(ws + off);  // N*128 fp32, layer-1 activations

    const int scanBlocks = (NS + SCAN_BS - 1) / SCAN_BS;
    const int layerGrid = (N + 127) / 128;

    // ---- build CSR by (relation, dst) ----
    zero_i<<<(NS + 255) / 256, 256, 0, stream>>>(cur, NS);
    count_kernel<<<(E + 255) / 256, 256, 0, stream>>>(ei, et, cur, E, N);
    scan1<<<scanBlocks, 256, 0, stream>>>(cur, row_start, bsum, NS);
    scan2<<<1, 512, 0, stream>>>(bsum, scanBlocks);
    scan3<<<scanBlocks, 256, 0, stream>>>(row_start, cur, bsum, NS);
    fill_kernel<<<(E + 255) / 256, 256, 0, stream>>>(ei, et, cur, col, E, N);

    // ---- weights -> bf16 transposed: layer1 [0..8], layer2 [9..17] ----
    wt_kernel<<<(8 * 16384 + 255) / 256, 256, 0, stream>>>(W1, WT, 8);
    wt_kernel<<<(1 * 16384 + 255) / 256, 256, 0, stream>>>(root1, WT + 8 * 16384, 1);
    wt_kernel<<<(8 * 16384 + 255) / 256, 256, 0, stream>>>(W2, WT + 9 * 16384, 8);
    wt_kernel<<<(1 * 16384 + 255) / 256, 256, 0, stream>>>(root2, WT + 17 * 16384, 1);

    // ---- layer 1: z = relu(agg(emb[ids]) + emb[ids]@root1 + b1) ----
    rgcn_layer<true, 0><<<layerGrid, 256, 0, stream>>>(
        row_start, col, x_ids, emb, WT, b1, z, N, E);

    // ---- layer 2: out = sigmoid(agg(z) + z@root2 + b2) ----
    rgcn_layer<false, 1><<<layerGrid, 256, 0, stream>>>(
        row_start, col, nullptr, z, WT + 9 * 16384, b2, out, N, E);
}